// Round 6
// baseline (414.206 us; speedup 1.0000x reference)
//
#include <hip/hip_runtime.h>
#include <hip/hip_bf16.h>
#include <math.h>

#define LSEQ 32768
#define HF   512
#define PS   128      // state_size/2
#define TWOP 256      // 2*PS (interleaved re,im)
#define NC   512      // scan chunks
#define CL   64       // chunk length  (NC*CL == LSEQ)

typedef __attribute__((ext_vector_type(8))) short short8v;   // 8 bf16 (4 VGPRs)
typedef __attribute__((ext_vector_type(4))) float f32x4;     // MFMA acc

// ---------------- helpers ----------------
__device__ __forceinline__ float sig_fast(float z) {
    return __builtin_amdgcn_rcpf(1.0f + __expf(-z));
}
__device__ __forceinline__ float gelu_fast(float v) {
    // tanh-gelu == v * sigmoid(2*0.79788456*(v + 0.044715 v^3))
    float z = 1.5957691216057308f * v * fmaf(0.044715f, v * v, 1.0f);
    return v * sig_fast(z);
}
__device__ __forceinline__ unsigned short bf16bits(float f) {
    __hip_bfloat16 h = __float2bfloat16(f);
    return *(unsigned short*)&h;
}
__device__ __forceinline__ float bf2f(unsigned short u) {
    unsigned v = ((unsigned)u) << 16;
    return *(float*)&v;
}
__device__ __forceinline__ unsigned pk2(float a, float b) {
    return ((unsigned)bf16bits(b) << 16) | bf16bits(a);
}
__device__ __forceinline__ void gload_lds16(const void* g, void* l) {
    __builtin_amdgcn_global_load_lds(
        (const __attribute__((address_space(1))) unsigned int*)g,
        (__attribute__((address_space(3))) unsigned int*)l, 16, 0, 0);
}

// ---------------- param prep ----------------
__global__ __launch_bounds__(128) void prep_lam_k(
    const float* __restrict__ lr_, const float* __restrict__ li_,
    const float* __restrict__ delta, float* lam, float* bls, float* lamPow)
{
    int p = threadIdx.x;
    float lr = lr_[p], li = li_[p];
    float step = expf(delta[p]);
    float s2 = 0.5f * step;
    float dr = 1.0f - s2 * lr, di = -s2 * li;
    float inv = 1.0f / (dr * dr + di * di);
    float blr = dr * inv, bli = -di * inv;
    float nr = 1.0f + s2 * lr, ni = s2 * li;
    float lbr = blr * nr - bli * ni;
    float lbi = blr * ni + bli * nr;
    lam[2 * p] = lbr; lam[2 * p + 1] = lbi;
    bls[2 * p] = blr * step; bls[2 * p + 1] = bli * step;
    float pr = 1.0f, pim = 0.0f;
    lamPow[2 * p] = 1.0f; lamPow[2 * p + 1] = 0.0f;
    for (int k = 1; k <= CL; k++) {
        float t = pr * lbr - pim * lbi;
        pim = pr * lbi + pim * lbr;
        pr = t;
        lamPow[k * TWOP + 2 * p] = pr;
        lamPow[k * TWOP + 2 * p + 1] = pim;
    }
}

// BwT[n=2p(+1)][h] bf16: pre-transposed B_bar (B'[N][K], K-contiguous)
__global__ __launch_bounds__(256) void prep_B_k(
    const float* __restrict__ b, const float* __restrict__ bls,
    unsigned short* __restrict__ bwt)
{
    int idx = blockIdx.x * 256 + threadIdx.x;   // over P*H
    int p = idx >> 9, h = idx & 511;
    float2 bb = *(const float2*)(b + ((size_t)p * HF + h) * 2);
    float sr = bls[2 * p], si = bls[2 * p + 1];
    bwt[(size_t)(2 * p) * HF + h]     = bf16bits(sr * bb.x - si * bb.y);
    bwt[(size_t)(2 * p + 1) * HF + h] = bf16bits(sr * bb.y + si * bb.x);
}

// CwT[h][2p(+1)] bf16: [N=H][K=2P] K-contiguous
__global__ __launch_bounds__(256) void prep_C_k(
    const float* __restrict__ c, unsigned short* __restrict__ cwt)
{
    int idx = blockIdx.x * 256 + threadIdx.x;   // over H*P
    int h = idx >> 7, p = idx & 127;
    float2 cc = *(const float2*)(c + ((size_t)h * PS + p) * 2);
    *(unsigned*)(cwt + (size_t)h * TWOP + 2 * p) = pk2(2.0f * cc.x, -2.0f * cc.y);
}

// w2T[n][k] bf16 = w2[k][n]
__global__ __launch_bounds__(256) void prep_w2_k(
    const float* __restrict__ w2, unsigned short* __restrict__ w2t)
{
    int idx = blockIdx.x * 256 + threadIdx.x;   // over H*H
    int n = idx >> 9, k = idx & 511;
    w2t[(size_t)n * HF + k] = bf16bits(w2[(size_t)k * HF + n]);
}

// ---------------- LayerNorm (bf16 out only) ----------------
__global__ __launch_bounds__(128) void ln_k(
    const float* __restrict__ x, const float* __restrict__ scale,
    const float* __restrict__ offs, unsigned short* __restrict__ xnbf)
{
    int row = blockIdx.x, t = threadIdx.x;
    const float4* xr = (const float4*)(x + (size_t)row * HF);
    float4 v = xr[t];
    float s = v.x + v.y + v.z + v.w;
    float q = v.x * v.x + v.y * v.y + v.z * v.z + v.w * v.w;
    #pragma unroll
    for (int off = 32; off > 0; off >>= 1) {
        s += __shfl_down(s, off);
        q += __shfl_down(q, off);
    }
    __shared__ float ss[2], qq[2];
    if ((t & 63) == 0) { ss[t >> 6] = s; qq[t >> 6] = q; }
    __syncthreads();
    float S = ss[0] + ss[1], Q = qq[0] + qq[1];
    float mean = S * (1.0f / HF);
    float var = Q * (1.0f / HF) - mean * mean;
    float rstd = rsqrtf(var + 1e-5f);
    float4 sc = ((const float4*)scale)[t];
    float4 of = ((const float4*)offs)[t];
    ushort4 hv;
    hv.x = bf16bits((v.x - mean) * rstd * sc.x + of.x);
    hv.y = bf16bits((v.y - mean) * rstd * sc.y + of.y);
    hv.z = bf16bits((v.z - mean) * rstd * sc.z + of.z);
    hv.w = bf16bits((v.w - mean) * rstd * sc.w + of.w);
    ((ushort4*)(xnbf + (size_t)row * HF))[t] = hv;
}

// ---------------- fused GEMM1 + local scan ----------------
// Bu-tile = xn * B_bar^T (128x128, K=512), per-column local scan over the
// 2 chunks (64 rows) in the tile; emits chunk finals F (fp32) and local xs (bf16).
__global__ __launch_bounds__(256) void g1scan_k(
    const unsigned short* __restrict__ A,   // XNBF [L][HF]
    const unsigned short* __restrict__ Bt,  // BWT  [TWOP][HF]
    unsigned short* __restrict__ xs16,      // [L][TWOP] bf16 local xs
    float* __restrict__ F,                  // [NC][TWOP]
    const float* __restrict__ lam)
{
    __shared__ float yt[128 * 128];         // 64KB; first 16KB doubles as staging
    unsigned short* As = (unsigned short*)yt;            // 128*32 bf16
    unsigned short* Bs = (unsigned short*)yt + 128 * 32; // 128*32 bf16
    const int K = HF;
    const int bm = blockIdx.y << 7;
    const int bn = blockIdx.x << 7;
    const int tid = threadIdx.x;
    const int lane = tid & 63;
    const int wid = tid >> 6;
    const int wr = wid >> 1, wc = wid & 1;

    f32x4 acc[4][4] = {};

    const int r0 = (wid << 5) + (lane >> 2);
    const int c0 = (lane & 3) << 3;
    const unsigned short* gA = A + (size_t)(bm + r0) * K + c0;
    const unsigned short* gB = Bt + (size_t)(bn + r0) * K + c0;
    unsigned short* lA0 = As + (wid << 5) * 32;
    unsigned short* lA1 = As + ((wid << 5) + 16) * 32;
    unsigned short* lB0 = Bs + (wid << 5) * 32;
    unsigned short* lB1 = Bs + ((wid << 5) + 16) * 32;
    const int aoff = ((wr << 6) + (lane & 15)) * 32 + ((lane >> 4) << 3);
    const int boff = ((wc << 6) + (lane & 15)) * 32 + ((lane >> 4) << 3);

    #pragma unroll
    for (int k0 = 0; k0 < HF; k0 += 32) {
        gload_lds16(gA + k0, lA0);
        gload_lds16(gA + k0 + (size_t)16 * K, lA1);
        gload_lds16(gB + k0, lB0);
        gload_lds16(gB + k0 + (size_t)16 * K, lB1);
        __syncthreads();
        short8v a[4], b[4];
        #pragma unroll
        for (int m = 0; m < 4; m++)
            a[m] = *(const short8v*)(As + aoff + (m << 4) * 32);
        #pragma unroll
        for (int n = 0; n < 4; n++)
            b[n] = *(const short8v*)(Bs + boff + (n << 4) * 32);
        #pragma unroll
        for (int m = 0; m < 4; m++)
            #pragma unroll
            for (int n = 0; n < 4; n++)
                acc[m][n] = __builtin_amdgcn_mfma_f32_16x16x32_bf16(
                    a[m], b[n], acc[m][n], 0, 0, 0);
        __syncthreads();
    }

    // acc -> LDS tile (row-major [128][128])
    #pragma unroll
    for (int m = 0; m < 4; m++) {
        const int rowb = (wr << 6) + (m << 4) + ((lane >> 4) << 2);
        #pragma unroll
        for (int n = 0; n < 4; n++) {
            const int col = (wc << 6) + (n << 4) + (lane & 15);
            #pragma unroll
            for (int j = 0; j < 4; j++)
                yt[(rowb + j) * 128 + col] = acc[m][n][j];
        }
    }
    __syncthreads();

    // local scan: 128 threads, each owns (chunk, complex pair)
    if (tid < 128) {
        int ch = tid >> 6, q = tid & 63;
        int pg = (blockIdx.x << 6) + q;          // global pair index
        float lr = lam[2 * pg], liv = lam[2 * pg + 1];
        float sr = 0.0f, si = 0.0f;
        float* col = yt + (ch << 6) * 128 + 2 * q;
        #pragma unroll 8
        for (int i = 0; i < CL; i++) {
            float ur = col[i * 128], ui = col[i * 128 + 1];
            float tr = lr * sr - liv * si + ur;
            float ti = lr * si + liv * sr + ui;
            sr = tr; si = ti;
            col[i * 128] = sr; col[i * 128 + 1] = si;
        }
        int cg = (blockIdx.y << 1) + ch;
        F[(size_t)cg * TWOP + (blockIdx.x << 7) + 2 * q] = sr;
        F[(size_t)cg * TWOP + (blockIdx.x << 7) + 2 * q + 1] = si;
    }
    __syncthreads();

    // write tile to global xs16 as bf16 (16B = 8 vals per chunk)
    #pragma unroll
    for (int j = 0; j < 8; j++) {
        int fl = j * 256 + tid;          // chunk id, 2048 total
        int r = fl >> 4, ck = fl & 15;
        float4 v0 = *(float4*)&yt[r * 128 + ck * 8];
        float4 v1 = *(float4*)&yt[r * 128 + ck * 8 + 4];
        uint4 o;
        o.x = pk2(v0.x, v0.y); o.y = pk2(v0.z, v0.w);
        o.z = pk2(v1.x, v1.y); o.w = pk2(v1.z, v1.w);
        *(uint4*)(xs16 + (size_t)(bm + r) * TWOP + bn + ck * 8) = o;
    }
}

// ---------------- merged carry scan + broadcast ----------------
// block c: compute carry G[c-1] by scanning F[0..c-1] (L2-resident, parallel
// across blocks), then xs[l] = xs16[l] + lam^(i+1)*carry  -> bf16 XSBF.
__global__ __launch_bounds__(128) void scanc_k(
    const unsigned short* __restrict__ xs16, const float* __restrict__ F,
    const float* __restrict__ lamPow, unsigned short* __restrict__ xsbf)
{
    int c = blockIdx.x, p = threadIdx.x;
    float lCr = lamPow[CL * TWOP + 2 * p], lCi = lamPow[CL * TWOP + 2 * p + 1];
    float gr = 0.0f, gi = 0.0f;
    for (int j = 0; j < c; j++) {
        float2 f = *(const float2*)(F + (size_t)j * TWOP + 2 * p);
        float tr = lCr * gr - lCi * gi + f.x;
        float ti = lCr * gi + lCi * gr + f.y;
        gr = tr; gi = ti;
    }
    size_t base = (size_t)c * CL * TWOP + 2 * p;
    #pragma unroll 4
    for (int i = 0; i < CL; i++) {
        float2 lp = *(const float2*)(lamPow + (size_t)(i + 1) * TWOP + 2 * p);
        unsigned u = *(const unsigned*)(xs16 + base + (size_t)i * TWOP);
        float vr = bf2f((unsigned short)(u & 0xffff)) + lp.x * gr - lp.y * gi;
        float vi = bf2f((unsigned short)(u >> 16))    + lp.x * gi + lp.y * gr;
        *(unsigned*)(xsbf + base + (size_t)i * TWOP) = pk2(vr, vi);
    }
}

// ---------------- bf16 MFMA GEMM (m97 structure, K templated) ----------------
// MODE 1: y = acc + e0[col]*bf2f(e1h[off]); o1 = bf16(y); o2 = bf16(gelu(y))
//         (e1h = bf16 xn; o2 overwrites e1h in place, same off per thread)
// MODE 2: outF = e2[off] + bf2f(e1h[off])*sigmoid(acc + e0[col])  (e1h = bf16 y)
template<int MODE, int KT>
__global__ __launch_bounds__(256) void mgemm_k(
    const unsigned short* __restrict__ A, const unsigned short* __restrict__ Bt,
    int N,
    const float* __restrict__ e0, const unsigned short* __restrict__ e1h,
    const float* __restrict__ e2, float* __restrict__ outF,
    unsigned short* __restrict__ o1, unsigned short* __restrict__ o2)
{
    __shared__ unsigned short As[128 * 32];
    __shared__ unsigned short Bs[128 * 32];
    const int bm = blockIdx.y << 7;
    const int bn = blockIdx.x << 7;
    const int tid = threadIdx.x;
    const int lane = tid & 63;
    const int wid = tid >> 6;
    const int wr = wid >> 1, wc = wid & 1;

    f32x4 acc[4][4] = {};

    const int r0 = (wid << 5) + (lane >> 2);
    const int c0 = (lane & 3) << 3;
    const unsigned short* gA = A + (size_t)(bm + r0) * KT + c0;
    const unsigned short* gB = Bt + (size_t)(bn + r0) * KT + c0;
    unsigned short* lA0 = As + (wid << 5) * 32;
    unsigned short* lA1 = As + ((wid << 5) + 16) * 32;
    unsigned short* lB0 = Bs + (wid << 5) * 32;
    unsigned short* lB1 = Bs + ((wid << 5) + 16) * 32;
    const int aoff = ((wr << 6) + (lane & 15)) * 32 + ((lane >> 4) << 3);
    const int boff = ((wc << 6) + (lane & 15)) * 32 + ((lane >> 4) << 3);

    #pragma unroll
    for (int k0 = 0; k0 < KT; k0 += 32) {
        gload_lds16(gA + k0, lA0);
        gload_lds16(gA + k0 + (size_t)16 * KT, lA1);
        gload_lds16(gB + k0, lB0);
        gload_lds16(gB + k0 + (size_t)16 * KT, lB1);
        __syncthreads();
        short8v a[4], b[4];
        #pragma unroll
        for (int m = 0; m < 4; m++)
            a[m] = *(const short8v*)(As + aoff + (m << 4) * 32);
        #pragma unroll
        for (int n = 0; n < 4; n++)
            b[n] = *(const short8v*)(Bs + boff + (n << 4) * 32);
        #pragma unroll
        for (int m = 0; m < 4; m++)
            #pragma unroll
            for (int n = 0; n < 4; n++)
                acc[m][n] = __builtin_amdgcn_mfma_f32_16x16x32_bf16(
                    a[m], b[n], acc[m][n], 0, 0, 0);
        __syncthreads();
    }

    #pragma unroll
    for (int m = 0; m < 4; m++) {
        const int rowb = bm + (wr << 6) + (m << 4) + ((lane >> 4) << 2);
        #pragma unroll
        for (int n = 0; n < 4; n++) {
            const int col = bn + (wc << 6) + (n << 4) + (lane & 15);
            const float e0v = e0[col];
            #pragma unroll
            for (int j = 0; j < 4; j++) {
                const size_t off = (size_t)(rowb + j) * N + col;
                float v = acc[m][n][j];
                if (MODE == 1) {
                    float y = v + e0v * bf2f(e1h[off]);
                    o1[off] = bf16bits(y);
                    o2[off] = bf16bits(gelu_fast(y));
                } else {
                    outF[off] = e2[off] + bf2f(e1h[off]) * sig_fast(v + e0v);
                }
            }
        }
    }
}

// ---------------- launch ----------------
extern "C" void kernel_launch(void* const* d_in, const int* in_sizes, int n_in,
                              void* d_out, int out_size, void* d_ws, size_t ws_size,
                              hipStream_t stream)
{
    const float* x      = (const float*)d_in[0];
    const float* lr     = (const float*)d_in[1];
    const float* li     = (const float*)d_in[2];
    const float* b      = (const float*)d_in[3];
    const float* c      = (const float*)d_in[4];
    const float* d      = (const float*)d_in[5];
    const float* delta  = (const float*)d_in[6];
    const float* nsc    = (const float*)d_in[7];
    const float* noff   = (const float*)d_in[8];
    const float* w2     = (const float*)d_in[9];
    const float* b2     = (const float*)d_in[10];
    float* out = (float*)d_out;

    unsigned short* XNBF = (unsigned short*)d_ws;       // [L,H] bf16: xn -> gelu(y)
    unsigned short* YBF  = XNBF + (size_t)LSEQ * HF;    // [L,H] bf16: y
    unsigned short* XS16 = YBF + (size_t)LSEQ * HF;     // [L,2P] bf16: local xs
    unsigned short* XSBF = XS16 + (size_t)LSEQ * TWOP;  // [L,2P] bf16: corrected xs
    unsigned short* BWT  = XSBF + (size_t)LSEQ * TWOP;  // [2P,H] bf16
    unsigned short* CWT  = BWT + (size_t)TWOP * HF;     // [H,2P] bf16
    unsigned short* W2T  = CWT + (size_t)HF * TWOP;     // [H,H] bf16
    float* lam    = (float*)(W2T + (size_t)HF * HF);
    float* bls    = lam + TWOP;
    float* lamPow = bls + TWOP;                         // [(CL+1),2P]
    float* F      = lamPow + (size_t)(CL + 1) * TWOP;   // [NC,2P]

    // params
    prep_lam_k<<<1, 128, 0, stream>>>(lr, li, delta, lam, bls, lamPow);
    prep_B_k<<<(PS * HF) / 256, 256, 0, stream>>>(b, bls, BWT);
    prep_C_k<<<(HF * PS) / 256, 256, 0, stream>>>(c, CWT);
    prep_w2_k<<<(HF * HF) / 256, 256, 0, stream>>>(w2, W2T);
    // layernorm -> bf16 xn
    ln_k<<<LSEQ, 128, 0, stream>>>(x, nsc, noff, XNBF);
    // Bu = xn * B_bar^T fused with local scan  [L,512]x[512,256]
    g1scan_k<<<dim3(TWOP >> 7, LSEQ >> 7), 256, 0, stream>>>(
        XNBF, BWT, XS16, F, lam);
    // per-block carry prefix + correction -> bf16 xs
    scanc_k<<<NC, 128, 0, stream>>>(XS16, F, lamPow, XSBF);
    // y = xs*Cw + d*xn -> bf16 y + bf16 gelu(y) (over xn)
    mgemm_k<1, TWOP><<<dim3(HF >> 7, LSEQ >> 7), 256, 0, stream>>>(
        XSBF, CWT, HF, d, XNBF, nullptr, nullptr, YBF, XNBF);
    // out = x + y*sigmoid(x1@w2 + b2)
    mgemm_k<2, HF><<<dim3(HF >> 7, LSEQ >> 7), 256, 0, stream>>>(
        XNBF, W2T, HF, b2, YBF, x, out, nullptr, nullptr);
}

// Round 9
// 239.582 us; speedup vs baseline: 1.7289x; 1.7289x over previous
//
#include <hip/hip_runtime.h>
#include <hip/hip_bf16.h>
#include <math.h>

#define LSEQ 32768
#define HF   512
#define PS   128      // state_size/2
#define TWOP 256      // 2*PS (interleaved re,im)
#define NC   512      // scan chunks
#define CL   64       // chunk length  (NC*CL == LSEQ)

typedef __attribute__((ext_vector_type(8))) short short8v;   // 8 bf16 (4 VGPRs)
typedef __attribute__((ext_vector_type(4))) float f32x4;     // MFMA acc

// ---------------- helpers ----------------
__device__ __forceinline__ float sig_fast(float z) {
    return __builtin_amdgcn_rcpf(1.0f + __expf(-z));
}
__device__ __forceinline__ float gelu_fast(float v) {
    // tanh-gelu == v * sigmoid(2*0.79788456*(v + 0.044715 v^3))
    float z = 1.5957691216057308f * v * fmaf(0.044715f, v * v, 1.0f);
    return v * sig_fast(z);
}
__device__ __forceinline__ unsigned short bf16bits(float f) {
    __hip_bfloat16 h = __float2bfloat16(f);
    return *(unsigned short*)&h;
}
__device__ __forceinline__ float bf2f(unsigned short u) {
    unsigned v = ((unsigned)u) << 16;
    return *(float*)&v;
}
__device__ __forceinline__ unsigned pk2(float a, float b) {
    return ((unsigned)bf16bits(b) << 16) | bf16bits(a);
}
__device__ __forceinline__ void gload_lds16(const void* g, void* l) {
    __builtin_amdgcn_global_load_lds(
        (const __attribute__((address_space(1))) unsigned int*)g,
        (__attribute__((address_space(3))) unsigned int*)l, 16, 0, 0);
}

// ---------------- param prep ----------------
__global__ __launch_bounds__(128) void prep_lam_k(
    const float* __restrict__ lr_, const float* __restrict__ li_,
    const float* __restrict__ delta, float* lam, float* bls, float* lamPow)
{
    int p = threadIdx.x;
    float lr = lr_[p], li = li_[p];
    float step = expf(delta[p]);
    float s2 = 0.5f * step;
    float dr = 1.0f - s2 * lr, di = -s2 * li;
    float inv = 1.0f / (dr * dr + di * di);
    float blr = dr * inv, bli = -di * inv;
    float nr = 1.0f + s2 * lr, ni = s2 * li;
    float lbr = blr * nr - bli * ni;
    float lbi = blr * ni + bli * nr;
    lam[2 * p] = lbr; lam[2 * p + 1] = lbi;
    bls[2 * p] = blr * step; bls[2 * p + 1] = bli * step;
    float pr = 1.0f, pim = 0.0f;
    lamPow[2 * p] = 1.0f; lamPow[2 * p + 1] = 0.0f;
    for (int k = 1; k <= CL; k++) {
        float t = pr * lbr - pim * lbi;
        pim = pr * lbi + pim * lbr;
        pr = t;
        lamPow[k * TWOP + 2 * p] = pr;
        lamPow[k * TWOP + 2 * p + 1] = pim;
    }
}

// BwT[n=2p(+1)][h] bf16: pre-transposed B_bar (B'[N][K], K-contiguous)
__global__ __launch_bounds__(256) void prep_B_k(
    const float* __restrict__ b, const float* __restrict__ bls,
    unsigned short* __restrict__ bwt)
{
    int idx = blockIdx.x * 256 + threadIdx.x;   // over P*H
    int p = idx >> 9, h = idx & 511;
    float2 bb = *(const float2*)(b + ((size_t)p * HF + h) * 2);
    float sr = bls[2 * p], si = bls[2 * p + 1];
    bwt[(size_t)(2 * p) * HF + h]     = bf16bits(sr * bb.x - si * bb.y);
    bwt[(size_t)(2 * p + 1) * HF + h] = bf16bits(sr * bb.y + si * bb.x);
}

// CwT[h][2p(+1)] bf16: [N=H][K=2P] K-contiguous
__global__ __launch_bounds__(256) void prep_C_k(
    const float* __restrict__ c, unsigned short* __restrict__ cwt)
{
    int idx = blockIdx.x * 256 + threadIdx.x;   // over H*P
    int h = idx >> 7, p = idx & 127;
    float2 cc = *(const float2*)(c + ((size_t)h * PS + p) * 2);
    *(unsigned*)(cwt + (size_t)h * TWOP + 2 * p) = pk2(2.0f * cc.x, -2.0f * cc.y);
}

// w2T[n][k] bf16 = w2[k][n]
__global__ __launch_bounds__(256) void prep_w2_k(
    const float* __restrict__ w2, unsigned short* __restrict__ w2t)
{
    int idx = blockIdx.x * 256 + threadIdx.x;   // over H*H
    int n = idx >> 9, k = idx & 511;
    w2t[(size_t)n * HF + k] = bf16bits(w2[(size_t)k * HF + n]);
}

// ---------------- LayerNorm (bf16 out only) ----------------
__global__ __launch_bounds__(128) void ln_k(
    const float* __restrict__ x, const float* __restrict__ scale,
    const float* __restrict__ offs, unsigned short* __restrict__ xnbf)
{
    int row = blockIdx.x, t = threadIdx.x;
    const float4* xr = (const float4*)(x + (size_t)row * HF);
    float4 v = xr[t];
    float s = v.x + v.y + v.z + v.w;
    float q = v.x * v.x + v.y * v.y + v.z * v.z + v.w * v.w;
    #pragma unroll
    for (int off = 32; off > 0; off >>= 1) {
        s += __shfl_down(s, off);
        q += __shfl_down(q, off);
    }
    __shared__ float ss[2], qq[2];
    if ((t & 63) == 0) { ss[t >> 6] = s; qq[t >> 6] = q; }
    __syncthreads();
    float S = ss[0] + ss[1], Q = qq[0] + qq[1];
    float mean = S * (1.0f / HF);
    float var = Q * (1.0f / HF) - mean * mean;
    float rstd = rsqrtf(var + 1e-5f);
    float4 sc = ((const float4*)scale)[t];
    float4 of = ((const float4*)offs)[t];
    ushort4 hv;
    hv.x = bf16bits((v.x - mean) * rstd * sc.x + of.x);
    hv.y = bf16bits((v.y - mean) * rstd * sc.y + of.y);
    hv.z = bf16bits((v.z - mean) * rstd * sc.z + of.z);
    hv.w = bf16bits((v.w - mean) * rstd * sc.w + of.w);
    ((ushort4*)(xnbf + (size_t)row * HF))[t] = hv;
}

// ---------------- fused GEMM1 + local scan ----------------
__global__ __launch_bounds__(256) void g1scan_k(
    const unsigned short* __restrict__ A,   // XNBF [L][HF]
    const unsigned short* __restrict__ Bt,  // BWT  [TWOP][HF]
    unsigned short* __restrict__ xs16,      // [L][TWOP] bf16 local xs
    float* __restrict__ F,                  // [NC][TWOP]
    const float* __restrict__ lam)
{
    __shared__ float yt[128 * 128];         // 64KB; first 16KB doubles as staging
    unsigned short* As = (unsigned short*)yt;            // 128*32 bf16
    unsigned short* Bs = (unsigned short*)yt + 128 * 32; // 128*32 bf16
    const int K = HF;
    // XCD-chunked swizzle (nwg=512, gx=2)
    int flat = (blockIdx.y << 1) + blockIdx.x;
    int f2 = (flat & 7) * 64 + (flat >> 3);
    const int bxi = f2 & 1, byi = f2 >> 1;
    const int bm = byi << 7;
    const int bn = bxi << 7;
    const int tid = threadIdx.x;
    const int lane = tid & 63;
    const int wid = tid >> 6;
    const int wr = wid >> 1, wc = wid & 1;

    f32x4 acc[4][4] = {};

    const int r0 = (wid << 5) + (lane >> 2);
    const int c0 = (lane & 3) << 3;
    const unsigned short* gA = A + (size_t)(bm + r0) * K + c0;
    const unsigned short* gB = Bt + (size_t)(bn + r0) * K + c0;
    unsigned short* lA0 = As + (wid << 5) * 32;
    unsigned short* lA1 = As + ((wid << 5) + 16) * 32;
    unsigned short* lB0 = Bs + (wid << 5) * 32;
    unsigned short* lB1 = Bs + ((wid << 5) + 16) * 32;
    const int aoff = ((wr << 6) + (lane & 15)) * 32 + ((lane >> 4) << 3);
    const int boff = ((wc << 6) + (lane & 15)) * 32 + ((lane >> 4) << 3);

    #pragma unroll
    for (int k0 = 0; k0 < HF; k0 += 32) {
        gload_lds16(gA + k0, lA0);
        gload_lds16(gA + k0 + (size_t)16 * K, lA1);
        gload_lds16(gB + k0, lB0);
        gload_lds16(gB + k0 + (size_t)16 * K, lB1);
        __syncthreads();
        short8v a[4], b[4];
        #pragma unroll
        for (int m = 0; m < 4; m++)
            a[m] = *(const short8v*)(As + aoff + (m << 4) * 32);
        #pragma unroll
        for (int n = 0; n < 4; n++)
            b[n] = *(const short8v*)(Bs + boff + (n << 4) * 32);
        #pragma unroll
        for (int m = 0; m < 4; m++)
            #pragma unroll
            for (int n = 0; n < 4; n++)
                acc[m][n] = __builtin_amdgcn_mfma_f32_16x16x32_bf16(
                    a[m], b[n], acc[m][n], 0, 0, 0);
        __syncthreads();
    }

    // acc -> LDS tile (row-major [128][128])
    #pragma unroll
    for (int m = 0; m < 4; m++) {
        const int rowb = (wr << 6) + (m << 4) + ((lane >> 4) << 2);
        #pragma unroll
        for (int n = 0; n < 4; n++) {
            const int col = (wc << 6) + (n << 4) + (lane & 15);
            #pragma unroll
            for (int j = 0; j < 4; j++)
                yt[(rowb + j) * 128 + col] = acc[m][n][j];
        }
    }
    __syncthreads();

    // local scan: 128 threads, each owns (chunk, complex pair)
    if (tid < 128) {
        int ch = tid >> 6, q = tid & 63;
        int pg = (bxi << 6) + q;                 // global pair index
        float lr = lam[2 * pg], liv = lam[2 * pg + 1];
        float sr = 0.0f, si = 0.0f;
        float* col = yt + (ch << 6) * 128 + 2 * q;
        #pragma unroll 8
        for (int i = 0; i < CL; i++) {
            float ur = col[i * 128], ui = col[i * 128 + 1];
            float tr = lr * sr - liv * si + ur;
            float ti = lr * si + liv * sr + ui;
            sr = tr; si = ti;
            col[i * 128] = sr; col[i * 128 + 1] = si;
        }
        int cg = (byi << 1) + ch;
        F[(size_t)cg * TWOP + (bxi << 7) + 2 * q] = sr;
        F[(size_t)cg * TWOP + (bxi << 7) + 2 * q + 1] = si;
    }
    __syncthreads();

    // write tile to global xs16 as bf16 (16B = 8 vals)
    #pragma unroll
    for (int j = 0; j < 8; j++) {
        int fl = j * 256 + tid;
        int r = fl >> 4, ck = fl & 15;
        float4 v0 = *(float4*)&yt[r * 128 + ck * 8];
        float4 v1 = *(float4*)&yt[r * 128 + ck * 8 + 4];
        uint4 o;
        o.x = pk2(v0.x, v0.y); o.y = pk2(v0.z, v0.w);
        o.z = pk2(v1.x, v1.y); o.w = pk2(v1.z, v1.w);
        *(uint4*)(xs16 + (size_t)(bm + r) * TWOP + bn + ck * 8) = o;
    }
}

// ---------------- carry scan: Kogge-Stone over chunk finals ----------------
// block = state pair p (128 blocks), 512 threads = chunks. G = inclusive scan.
__global__ __launch_bounds__(512) void carry_k(
    const float* __restrict__ F, float* __restrict__ G,
    const float* __restrict__ lamPow)
{
    __shared__ float2 buf[NC];
    int c = threadIdx.x, p = blockIdx.x;
    float2 f = *(const float2*)(F + (size_t)c * TWOP + 2 * p);
    buf[c] = f;
    float aR = lamPow[CL * TWOP + 2 * p], aI = lamPow[CL * TWOP + 2 * p + 1];
    __syncthreads();
    #pragma unroll
    for (int d = 1; d < NC; d <<= 1) {
        bool act = (c >= d);
        float2 pv = act ? buf[c - d] : make_float2(0.0f, 0.0f);
        __syncthreads();
        if (act) {
            float2 cur = buf[c];
            cur.x += aR * pv.x - aI * pv.y;
            cur.y += aR * pv.y + aI * pv.x;
            buf[c] = cur;
        }
        __syncthreads();
        float nR = aR * aR - aI * aI;
        float nI = 2.0f * aR * aI;
        aR = nR; aI = nI;
    }
    *(float2*)(G + (size_t)c * TWOP + 2 * p) = buf[c];
}

// ---------------- parallel carry correction ----------------
// block = (chunk c, quarter qq): 2048 blocks x 128 threads, 16 rows each.
__global__ __launch_bounds__(128) void fix_k(
    const unsigned short* __restrict__ xs16, const float* __restrict__ G,
    const float* __restrict__ lamPow, unsigned short* __restrict__ xsbf)
{
    int bc = blockIdx.x;
    int c = bc >> 2, qq = bc & 3;
    int p = threadIdx.x;
    float gr = 0.0f, gi = 0.0f;
    if (c > 0) {
        float2 g = *(const float2*)(G + (size_t)(c - 1) * TWOP + 2 * p);
        gr = g.x; gi = g.y;
    }
    size_t base = ((size_t)c * CL + (qq << 4)) * TWOP + 2 * p;
    #pragma unroll
    for (int i = 0; i < 16; i++) {
        float2 lp = *(const float2*)(lamPow + (size_t)((qq << 4) + i + 1) * TWOP + 2 * p);
        unsigned u = *(const unsigned*)(xs16 + base + (size_t)i * TWOP);
        float vr = bf2f((unsigned short)(u & 0xffff)) + lp.x * gr - lp.y * gi;
        float vi = bf2f((unsigned short)(u >> 16))    + lp.x * gi + lp.y * gr;
        *(unsigned*)(xsbf + base + (size_t)i * TWOP) = pk2(vr, vi);
    }
}

// ---------------- bf16 MFMA GEMM (m97 structure, vectorized epilogue) -------
// MODE 1: y = acc + e0[col]*xn;  o1 = bf16(y); o2 = bf16(gelu(y))  (o2 aliases e1h)
// MODE 2: outF = e2 + bf2f(e1h)*sigmoid(acc + e0[col])
template<int MODE, int KT, int NT>
__global__ __launch_bounds__(256) void mgemm_k(
    const unsigned short* __restrict__ A, const unsigned short* __restrict__ Bt,
    const float* __restrict__ e0, const unsigned short* __restrict__ e1h,
    const float* __restrict__ e2, float* __restrict__ outF,
    unsigned short* __restrict__ o1, unsigned short* __restrict__ o2)
{
    __shared__ float smem[4224];            // 16.5KB: staging (16KB) U epilogue tile
    unsigned short* As = (unsigned short*)smem;      // 128*32 bf16 = 8KB
    unsigned short* Bs = As + 128 * 32;              // 8KB
    float* eb = smem;                                 // [32][132] padded fp32

    // XCD-chunked swizzle (nwg = (NT>>7)*256, divisible by 8)
    constexpr int GX = NT >> 7;
    int flat = blockIdx.y * GX + blockIdx.x;
    constexpr int NWG = GX * (LSEQ >> 7);
    int f2 = (flat & 7) * (NWG >> 3) + (flat >> 3);
    const int bm = (f2 / GX) << 7;
    const int bn = (f2 % GX) << 7;

    const int tid = threadIdx.x;
    const int lane = tid & 63;
    const int wid = tid >> 6;
    const int wr = wid >> 1, wc = wid & 1;

    f32x4 acc[4][4] = {};

    const int r0 = (wid << 5) + (lane >> 2);
    const int c0 = (lane & 3) << 3;
    const unsigned short* gA = A + (size_t)(bm + r0) * KT + c0;
    const unsigned short* gB = Bt + (size_t)(bn + r0) * KT + c0;
    unsigned short* lA0 = As + (wid << 5) * 32;
    unsigned short* lA1 = As + ((wid << 5) + 16) * 32;
    unsigned short* lB0 = Bs + (wid << 5) * 32;
    unsigned short* lB1 = Bs + ((wid << 5) + 16) * 32;
    const int aoff = ((wr << 6) + (lane & 15)) * 32 + ((lane >> 4) << 3);
    const int boff = ((wc << 6) + (lane & 15)) * 32 + ((lane >> 4) << 3);

    #pragma unroll
    for (int k0 = 0; k0 < KT; k0 += 32) {
        gload_lds16(gA + k0, lA0);
        gload_lds16(gA + k0 + (size_t)16 * KT, lA1);
        gload_lds16(gB + k0, lB0);
        gload_lds16(gB + k0 + (size_t)16 * KT, lB1);
        __syncthreads();
        short8v a[4], b[4];
        #pragma unroll
        for (int m = 0; m < 4; m++)
            a[m] = *(const short8v*)(As + aoff + (m << 4) * 32);
        #pragma unroll
        for (int n = 0; n < 4; n++)
            b[n] = *(const short8v*)(Bs + boff + (n << 4) * 32);
        #pragma unroll
        for (int m = 0; m < 4; m++)
            #pragma unroll
            for (int n = 0; n < 4; n++)
                acc[m][n] = __builtin_amdgcn_mfma_f32_16x16x32_bf16(
                    a[m], b[n], acc[m][n], 0, 0, 0);
        __syncthreads();
    }

    // epilogue: 4 passes of 32 rows through padded LDS, fully-coalesced global I/O
    #pragma unroll
    for (int p = 0; p < 4; p++) {
        if ((p >> 1) == wr) {
            const int mb = (p & 1) << 1;
            #pragma unroll
            for (int mm = 0; mm < 2; mm++) {
                const int lrow = (mm << 4) + ((lane >> 4) << 2);
                #pragma unroll
                for (int n = 0; n < 4; n++) {
                    const int col = (wc << 6) + (n << 4) + (lane & 15);
                    #pragma unroll
                    for (int j = 0; j < 4; j++)
                        eb[(lrow + j) * 132 + col] = acc[mb + mm][n][j];
                }
            }
        }
        __syncthreads();
        #pragma unroll
        for (int i = 0; i < 4; i++) {
            int idx = (i << 8) + tid;        // 0..1023
            int row = idx >> 5, c4 = idx & 31;
            int gr = bm + (p << 5) + row;
            int gc = bn + (c4 << 2);
            size_t off = (size_t)gr * NT + gc;
            float4 v = *(float4*)&eb[row * 132 + (c4 << 2)];
            float4 e0v = *(const float4*)(e0 + gc);
            if (MODE == 1) {
                ushort4 xv = *(const ushort4*)(e1h + off);
                float y0 = v.x + e0v.x * bf2f(xv.x);
                float y1 = v.y + e0v.y * bf2f(xv.y);
                float y2 = v.z + e0v.z * bf2f(xv.z);
                float y3 = v.w + e0v.w * bf2f(xv.w);
                ushort4 a1, a2;
                a1.x = bf16bits(y0); a1.y = bf16bits(y1);
                a1.z = bf16bits(y2); a1.w = bf16bits(y3);
                a2.x = bf16bits(gelu_fast(y0)); a2.y = bf16bits(gelu_fast(y1));
                a2.z = bf16bits(gelu_fast(y2)); a2.w = bf16bits(gelu_fast(y3));
                *(ushort4*)(o1 + off) = a1;
                *(ushort4*)(o2 + off) = a2;
            } else {
                ushort4 yv = *(const ushort4*)(e1h + off);
                float4 xv = *(const float4*)(e2 + off);
                float4 o;
                o.x = xv.x + bf2f(yv.x) * sig_fast(v.x + e0v.x);
                o.y = xv.y + bf2f(yv.y) * sig_fast(v.y + e0v.y);
                o.z = xv.z + bf2f(yv.z) * sig_fast(v.z + e0v.z);
                o.w = xv.w + bf2f(yv.w) * sig_fast(v.w + e0v.w);
                *(float4*)(outF + off) = o;
            }
        }
        __syncthreads();
    }
}

// ---------------- launch ----------------
extern "C" void kernel_launch(void* const* d_in, const int* in_sizes, int n_in,
                              void* d_out, int out_size, void* d_ws, size_t ws_size,
                              hipStream_t stream)
{
    const float* x      = (const float*)d_in[0];
    const float* lr     = (const float*)d_in[1];
    const float* li     = (const float*)d_in[2];
    const float* b      = (const float*)d_in[3];
    const float* c      = (const float*)d_in[4];
    const float* d      = (const float*)d_in[5];
    const float* delta  = (const float*)d_in[6];
    const float* nsc    = (const float*)d_in[7];
    const float* noff   = (const float*)d_in[8];
    const float* w2     = (const float*)d_in[9];
    const float* b2     = (const float*)d_in[10];
    float* out = (float*)d_out;

    unsigned short* XNBF = (unsigned short*)d_ws;       // [L,H] bf16: xn -> gelu(y)
    unsigned short* YBF  = XNBF + (size_t)LSEQ * HF;    // [L,H] bf16: y
    unsigned short* XS16 = YBF + (size_t)LSEQ * HF;     // [L,2P] bf16: local xs
    unsigned short* XSBF = XS16 + (size_t)LSEQ * TWOP;  // [L,2P] bf16: corrected xs
    unsigned short* BWT  = XSBF + (size_t)LSEQ * TWOP;  // [2P,H] bf16
    unsigned short* CWT  = BWT + (size_t)TWOP * HF;     // [H,2P] bf16
    unsigned short* W2T  = CWT + (size_t)HF * TWOP;     // [H,H] bf16
    float* lam    = (float*)(W2T + (size_t)HF * HF);
    float* bls    = lam + TWOP;
    float* lamPow = bls + TWOP;                         // [(CL+1),2P]
    float* F      = lamPow + (size_t)(CL + 1) * TWOP;   // [NC,2P]
    float* G      = F + (size_t)NC * TWOP;              // [NC,2P]

    // params
    prep_lam_k<<<1, 128, 0, stream>>>(lr, li, delta, lam, bls, lamPow);
    prep_B_k<<<(PS * HF) / 256, 256, 0, stream>>>(b, bls, BWT);
    prep_C_k<<<(HF * PS) / 256, 256, 0, stream>>>(c, CWT);
    prep_w2_k<<<(HF * HF) / 256, 256, 0, stream>>>(w2, W2T);
    // layernorm -> bf16 xn
    ln_k<<<LSEQ, 128, 0, stream>>>(x, nsc, noff, XNBF);
    // Bu = xn * B_bar^T fused with local scan  [L,512]x[512,256]
    g1scan_k<<<dim3(TWOP >> 7, LSEQ >> 7), 256, 0, stream>>>(
        XNBF, BWT, XS16, F, lam);
    // Kogge-Stone carry scan over chunk finals
    carry_k<<<PS, 512, 0, stream>>>(F, G, lamPow);
    // parallel carry correction -> bf16 xs
    fix_k<<<NC * 4, 128, 0, stream>>>(XS16, G, lamPow, XSBF);
    // y = xs*Cw + d*xn -> bf16 y + bf16 gelu(y) (over xn)
    mgemm_k<1, TWOP, HF><<<dim3(4, LSEQ >> 7), 256, 0, stream>>>(
        XSBF, CWT, d, XNBF, nullptr, nullptr, YBF, XNBF);
    // out = x + y*sigmoid(x1@w2 + b2)
    mgemm_k<2, HF, HF><<<dim3(4, LSEQ >> 7), 256, 0, stream>>>(
        XNBF, W2T, b2, YBF, x, out, nullptr, nullptr);
}

// Round 10
// 236.609 us; speedup vs baseline: 1.7506x; 1.0126x over previous
//
#include <hip/hip_runtime.h>
#include <hip/hip_bf16.h>
#include <math.h>

#define LSEQ 32768
#define HF   512
#define PS   128      // state_size/2
#define TWOP 256      // 2*PS (interleaved re,im)
#define NC   512      // scan chunks
#define CL   64       // chunk length  (NC*CL == LSEQ)

typedef __attribute__((ext_vector_type(8))) short short8v;   // 8 bf16 (4 VGPRs)
typedef __attribute__((ext_vector_type(4))) float f32x4;     // MFMA acc

// ---------------- helpers ----------------
__device__ __forceinline__ float sig_fast(float z) {
    return __builtin_amdgcn_rcpf(1.0f + __expf(-z));
}
__device__ __forceinline__ float gelu_fast(float v) {
    // tanh-gelu == v * sigmoid(2*0.79788456*(v + 0.044715 v^3))
    float z = 1.5957691216057308f * v * fmaf(0.044715f, v * v, 1.0f);
    return v * sig_fast(z);
}
__device__ __forceinline__ unsigned short bf16bits(float f) {
    __hip_bfloat16 h = __float2bfloat16(f);
    return *(unsigned short*)&h;
}
__device__ __forceinline__ float bf2f(unsigned short u) {
    unsigned v = ((unsigned)u) << 16;
    return *(float*)&v;
}
__device__ __forceinline__ unsigned pk2(float a, float b) {
    return ((unsigned)bf16bits(b) << 16) | bf16bits(a);
}
__device__ __forceinline__ void gload_lds16(const void* g, void* l) {
    __builtin_amdgcn_global_load_lds(
        (const __attribute__((address_space(1))) unsigned int*)g,
        (__attribute__((address_space(3))) unsigned int*)l, 16, 0, 0);
}
__device__ __forceinline__ void wait_vm0_barrier() {
    asm volatile("s_waitcnt vmcnt(0)" ::: "memory");
    __builtin_amdgcn_s_barrier();
}

// ---------------- param prep ----------------
__global__ __launch_bounds__(128) void prep_lam_k(
    const float* __restrict__ lr_, const float* __restrict__ li_,
    const float* __restrict__ delta, float* lam, float* bls, float* lamPow)
{
    int p = threadIdx.x;
    float lr = lr_[p], li = li_[p];
    float step = expf(delta[p]);
    float s2 = 0.5f * step;
    float dr = 1.0f - s2 * lr, di = -s2 * li;
    float inv = 1.0f / (dr * dr + di * di);
    float blr = dr * inv, bli = -di * inv;
    float nr = 1.0f + s2 * lr, ni = s2 * li;
    float lbr = blr * nr - bli * ni;
    float lbi = blr * ni + bli * nr;
    lam[2 * p] = lbr; lam[2 * p + 1] = lbi;
    bls[2 * p] = blr * step; bls[2 * p + 1] = bli * step;
    float pr = 1.0f, pim = 0.0f;
    lamPow[2 * p] = 1.0f; lamPow[2 * p + 1] = 0.0f;
    for (int k = 1; k <= CL; k++) {
        float t = pr * lbr - pim * lbi;
        pim = pr * lbi + pim * lbr;
        pr = t;
        lamPow[k * TWOP + 2 * p] = pr;
        lamPow[k * TWOP + 2 * p + 1] = pim;
    }
}

// BwT[n=2p(+1)][h] bf16: pre-transposed B_bar (B'[N][K], K-contiguous)
__global__ __launch_bounds__(256) void prep_B_k(
    const float* __restrict__ b, const float* __restrict__ bls,
    unsigned short* __restrict__ bwt)
{
    int idx = blockIdx.x * 256 + threadIdx.x;   // over P*H
    int p = idx >> 9, h = idx & 511;
    float2 bb = *(const float2*)(b + ((size_t)p * HF + h) * 2);
    float sr = bls[2 * p], si = bls[2 * p + 1];
    bwt[(size_t)(2 * p) * HF + h]     = bf16bits(sr * bb.x - si * bb.y);
    bwt[(size_t)(2 * p + 1) * HF + h] = bf16bits(sr * bb.y + si * bb.x);
}

// CwT[h][2p(+1)] bf16: [N=H][K=2P] K-contiguous
__global__ __launch_bounds__(256) void prep_C_k(
    const float* __restrict__ c, unsigned short* __restrict__ cwt)
{
    int idx = blockIdx.x * 256 + threadIdx.x;   // over H*P
    int h = idx >> 7, p = idx & 127;
    float2 cc = *(const float2*)(c + ((size_t)h * PS + p) * 2);
    *(unsigned*)(cwt + (size_t)h * TWOP + 2 * p) = pk2(2.0f * cc.x, -2.0f * cc.y);
}

// w2T[n][k] bf16 = w2[k][n]
__global__ __launch_bounds__(256) void prep_w2_k(
    const float* __restrict__ w2, unsigned short* __restrict__ w2t)
{
    int idx = blockIdx.x * 256 + threadIdx.x;   // over H*H
    int n = idx >> 9, k = idx & 511;
    w2t[(size_t)n * HF + k] = bf16bits(w2[(size_t)k * HF + n]);
}

// ---------------- LayerNorm (bf16 out only) ----------------
__global__ __launch_bounds__(128) void ln_k(
    const float* __restrict__ x, const float* __restrict__ scale,
    const float* __restrict__ offs, unsigned short* __restrict__ xnbf)
{
    int row = blockIdx.x, t = threadIdx.x;
    const float4* xr = (const float4*)(x + (size_t)row * HF);
    float4 v = xr[t];
    float s = v.x + v.y + v.z + v.w;
    float q = v.x * v.x + v.y * v.y + v.z * v.z + v.w * v.w;
    #pragma unroll
    for (int off = 32; off > 0; off >>= 1) {
        s += __shfl_down(s, off);
        q += __shfl_down(q, off);
    }
    __shared__ float ss[2], qq[2];
    if ((t & 63) == 0) { ss[t >> 6] = s; qq[t >> 6] = q; }
    __syncthreads();
    float S = ss[0] + ss[1], Q = qq[0] + qq[1];
    float mean = S * (1.0f / HF);
    float var = Q * (1.0f / HF) - mean * mean;
    float rstd = rsqrtf(var + 1e-5f);
    float4 sc = ((const float4*)scale)[t];
    float4 of = ((const float4*)offs)[t];
    ushort4 hv;
    hv.x = bf16bits((v.x - mean) * rstd * sc.x + of.x);
    hv.y = bf16bits((v.y - mean) * rstd * sc.y + of.y);
    hv.z = bf16bits((v.z - mean) * rstd * sc.z + of.z);
    hv.w = bf16bits((v.w - mean) * rstd * sc.w + of.w);
    ((ushort4*)(xnbf + (size_t)row * HF))[t] = hv;
}

// ---------------- fused GEMM1 + local scan (2-phase pipelined) ----------------
__global__ __launch_bounds__(256) void g1scan_k(
    const unsigned short* __restrict__ A,   // XNBF [L][HF]
    const unsigned short* __restrict__ Bt,  // BWT  [TWOP][HF]
    unsigned short* __restrict__ xs16,      // [L][TWOP] bf16 local xs
    float* __restrict__ F,                  // [NC][TWOP]
    const float* __restrict__ lam)
{
    __shared__ float yt[128 * 128];         // 64KB; first 32KB doubles as dbuf staging
    unsigned short* Sb = (unsigned short*)yt;   // buf b: A at b*8192, B at b*8192+4096
    const int K = HF;
    // XCD-chunked swizzle (nwg=512, gx=2)
    int flat = (blockIdx.y << 1) + blockIdx.x;
    int f2 = (flat & 7) * 64 + (flat >> 3);
    const int bxi = f2 & 1, byi = f2 >> 1;
    const int bm = byi << 7;
    const int bn = bxi << 7;
    const int tid = threadIdx.x;
    const int lane = tid & 63;
    const int wid = tid >> 6;
    const int wr = wid >> 1, wc = wid & 1;

    f32x4 acc[4][4] = {};

    const int r0 = (wid << 5) + (lane >> 2);
    const int c0 = (lane & 3) << 3;
    const unsigned short* gA = A + (size_t)(bm + r0) * K + c0;
    const unsigned short* gB = Bt + (size_t)(bn + r0) * K + c0;
    const int stA0 = (wid << 5) * 32;
    const int stA1 = ((wid << 5) + 16) * 32;
    const int aoff = ((wr << 6) + (lane & 15)) * 32 + ((lane >> 4) << 3);
    const int boff = ((wc << 6) + (lane & 15)) * 32 + ((lane >> 4) << 3);

    #define G1_STAGE(b, k0) do { \
        gload_lds16(gA + (k0), Sb + (b) * 8192 + stA0); \
        gload_lds16(gA + (k0) + (size_t)16 * K, Sb + (b) * 8192 + stA1); \
        gload_lds16(gB + (k0), Sb + (b) * 8192 + 4096 + stA0); \
        gload_lds16(gB + (k0) + (size_t)16 * K, Sb + (b) * 8192 + 4096 + stA1); \
    } while (0)
    #define G1_COMPUTE(b) do { \
        short8v a_[4], b_[4]; \
        _Pragma("unroll") \
        for (int m = 0; m < 4; m++) \
            a_[m] = *(const short8v*)(Sb + (b) * 8192 + aoff + (m << 4) * 32); \
        _Pragma("unroll") \
        for (int n = 0; n < 4; n++) \
            b_[n] = *(const short8v*)(Sb + (b) * 8192 + 4096 + boff + (n << 4) * 32); \
        _Pragma("unroll") \
        for (int m = 0; m < 4; m++) \
            _Pragma("unroll") \
            for (int n = 0; n < 4; n++) \
                acc[m][n] = __builtin_amdgcn_mfma_f32_16x16x32_bf16( \
                    a_[m], b_[n], acc[m][n], 0, 0, 0); \
    } while (0)

    G1_STAGE(0, 0);
    wait_vm0_barrier();
    #pragma unroll
    for (int t = 0; t < 16; ++t) {
        const int cur = t & 1;
        if (t + 1 < 16) G1_STAGE(cur ^ 1, (t + 1) << 5);
        G1_COMPUTE(cur);
        wait_vm0_barrier();
    }

    // acc -> LDS tile (row-major [128][128])
    #pragma unroll
    for (int m = 0; m < 4; m++) {
        const int rowb = (wr << 6) + (m << 4) + ((lane >> 4) << 2);
        #pragma unroll
        for (int n = 0; n < 4; n++) {
            const int col = (wc << 6) + (n << 4) + (lane & 15);
            #pragma unroll
            for (int j = 0; j < 4; j++)
                yt[(rowb + j) * 128 + col] = acc[m][n][j];
        }
    }
    __syncthreads();

    // local scan: 128 threads, each owns (chunk, complex pair)
    if (tid < 128) {
        int ch = tid >> 6, q = tid & 63;
        int pg = (bxi << 6) + q;                 // global pair index
        float lr = lam[2 * pg], liv = lam[2 * pg + 1];
        float sr = 0.0f, si = 0.0f;
        float* col = yt + (ch << 6) * 128 + 2 * q;
        #pragma unroll 8
        for (int i = 0; i < CL; i++) {
            float ur = col[i * 128], ui = col[i * 128 + 1];
            float tr = lr * sr - liv * si + ur;
            float ti = lr * si + liv * sr + ui;
            sr = tr; si = ti;
            col[i * 128] = sr; col[i * 128 + 1] = si;
        }
        int cg = (byi << 1) + ch;
        F[(size_t)cg * TWOP + (bxi << 7) + 2 * q] = sr;
        F[(size_t)cg * TWOP + (bxi << 7) + 2 * q + 1] = si;
    }
    __syncthreads();

    // write tile to global xs16 as bf16 (16B = 8 vals)
    #pragma unroll
    for (int j = 0; j < 8; j++) {
        int fl = j * 256 + tid;
        int r = fl >> 4, ck = fl & 15;
        float4 v0 = *(float4*)&yt[r * 128 + ck * 8];
        float4 v1 = *(float4*)&yt[r * 128 + ck * 8 + 4];
        uint4 o;
        o.x = pk2(v0.x, v0.y); o.y = pk2(v0.z, v0.w);
        o.z = pk2(v1.x, v1.y); o.w = pk2(v1.z, v1.w);
        *(uint4*)(xs16 + (size_t)(bm + r) * TWOP + bn + ck * 8) = o;
    }
}

// ---------------- carry scan: Kogge-Stone over chunk finals ----------------
// block = state pair p (128 blocks), 512 threads = chunks. G = inclusive scan.
__global__ __launch_bounds__(512) void carry_k(
    const float* __restrict__ F, float* __restrict__ G,
    const float* __restrict__ lamPow)
{
    __shared__ float2 buf[NC];
    int c = threadIdx.x, p = blockIdx.x;
    float2 f = *(const float2*)(F + (size_t)c * TWOP + 2 * p);
    buf[c] = f;
    float aR = lamPow[CL * TWOP + 2 * p], aI = lamPow[CL * TWOP + 2 * p + 1];
    __syncthreads();
    #pragma unroll
    for (int d = 1; d < NC; d <<= 1) {
        bool act = (c >= d);
        float2 pv = act ? buf[c - d] : make_float2(0.0f, 0.0f);
        __syncthreads();
        if (act) {
            float2 cur = buf[c];
            cur.x += aR * pv.x - aI * pv.y;
            cur.y += aR * pv.y + aI * pv.x;
            buf[c] = cur;
        }
        __syncthreads();
        float nR = aR * aR - aI * aI;
        float nI = 2.0f * aR * aI;
        aR = nR; aI = nI;
    }
    *(float2*)(G + (size_t)c * TWOP + 2 * p) = buf[c];
}

// ---------------- parallel carry correction ----------------
// block = (chunk c, quarter qq): 2048 blocks x 128 threads, 16 rows each.
__global__ __launch_bounds__(128) void fix_k(
    const unsigned short* __restrict__ xs16, const float* __restrict__ G,
    const float* __restrict__ lamPow, unsigned short* __restrict__ xsbf)
{
    int bc = blockIdx.x;
    int c = bc >> 2, qq = bc & 3;
    int p = threadIdx.x;
    float gr = 0.0f, gi = 0.0f;
    if (c > 0) {
        float2 g = *(const float2*)(G + (size_t)(c - 1) * TWOP + 2 * p);
        gr = g.x; gi = g.y;
    }
    size_t base = ((size_t)c * CL + (qq << 4)) * TWOP + 2 * p;
    #pragma unroll
    for (int i = 0; i < 16; i++) {
        float2 lp = *(const float2*)(lamPow + (size_t)((qq << 4) + i + 1) * TWOP + 2 * p);
        unsigned u = *(const unsigned*)(xs16 + base + (size_t)i * TWOP);
        float vr = bf2f((unsigned short)(u & 0xffff)) + lp.x * gr - lp.y * gi;
        float vi = bf2f((unsigned short)(u >> 16))    + lp.x * gi + lp.y * gr;
        *(unsigned*)(xsbf + base + (size_t)i * TWOP) = pk2(vr, vi);
    }
}

// ---------------- bf16 MFMA GEMM (2-phase pipelined, vectorized epilogue) ----
// MODE 1: y = acc + e0[col]*xn;  o1 = bf16(y); o2 = bf16(gelu(y))  (o2 aliases e1h)
// MODE 2: outF = e2 + bf2f(e1h)*sigmoid(acc + e0[col])
template<int MODE, int KT, int NT>
__global__ __launch_bounds__(256) void mgemm_k(
    const unsigned short* __restrict__ A, const unsigned short* __restrict__ Bt,
    const float* __restrict__ e0, const unsigned short* __restrict__ e1h,
    const float* __restrict__ e2, float* __restrict__ outF,
    unsigned short* __restrict__ o1, unsigned short* __restrict__ o2)
{
    __shared__ float smem[8192];            // 32KB: dbuf staging; eb aliases base
    unsigned short* Sb = (unsigned short*)smem; // buf b: A at b*8192, B at b*8192+4096
    float* eb = smem;                            // [32][132] padded fp32 (16.9KB)

    // XCD-chunked swizzle (nwg = (NT>>7)*256, divisible by 8)
    constexpr int GX = NT >> 7;
    int flat = blockIdx.y * GX + blockIdx.x;
    constexpr int NWG = GX * (LSEQ >> 7);
    int f2 = (flat & 7) * (NWG >> 3) + (flat >> 3);
    const int bm = (f2 / GX) << 7;
    const int bn = (f2 % GX) << 7;

    const int tid = threadIdx.x;
    const int lane = tid & 63;
    const int wid = tid >> 6;
    const int wr = wid >> 1, wc = wid & 1;

    f32x4 acc[4][4] = {};

    const int r0 = (wid << 5) + (lane >> 2);
    const int c0 = (lane & 3) << 3;
    const unsigned short* gA = A + (size_t)(bm + r0) * KT + c0;
    const unsigned short* gB = Bt + (size_t)(bn + r0) * KT + c0;
    const int stA0 = (wid << 5) * 32;
    const int stA1 = ((wid << 5) + 16) * 32;
    const int aoff = ((wr << 6) + (lane & 15)) * 32 + ((lane >> 4) << 3);
    const int boff = ((wc << 6) + (lane & 15)) * 32 + ((lane >> 4) << 3);
    constexpr int NSTEP = KT >> 5;

    #define MG_STAGE(b, k0) do { \
        gload_lds16(gA + (k0), Sb + (b) * 8192 + stA0); \
        gload_lds16(gA + (k0) + (size_t)16 * KT, Sb + (b) * 8192 + stA1); \
        gload_lds16(gB + (k0), Sb + (b) * 8192 + 4096 + stA0); \
        gload_lds16(gB + (k0) + (size_t)16 * KT, Sb + (b) * 8192 + 4096 + stA1); \
    } while (0)
    #define MG_COMPUTE(b) do { \
        short8v a_[4], b_[4]; \
        _Pragma("unroll") \
        for (int m = 0; m < 4; m++) \
            a_[m] = *(const short8v*)(Sb + (b) * 8192 + aoff + (m << 4) * 32); \
        _Pragma("unroll") \
        for (int n = 0; n < 4; n++) \
            b_[n] = *(const short8v*)(Sb + (b) * 8192 + 4096 + boff + (n << 4) * 32); \
        _Pragma("unroll") \
        for (int m = 0; m < 4; m++) \
            _Pragma("unroll") \
            for (int n = 0; n < 4; n++) \
                acc[m][n] = __builtin_amdgcn_mfma_f32_16x16x32_bf16( \
                    a_[m], b_[n], acc[m][n], 0, 0, 0); \
    } while (0)

    MG_STAGE(0, 0);
    wait_vm0_barrier();
    #pragma unroll
    for (int t = 0; t < NSTEP; ++t) {
        const int cur = t & 1;
        if (t + 1 < NSTEP) MG_STAGE(cur ^ 1, (t + 1) << 5);
        MG_COMPUTE(cur);
        wait_vm0_barrier();
    }

    // epilogue: 4 passes of 32 rows through padded LDS, fully-coalesced global I/O
    #pragma unroll
    for (int p = 0; p < 4; p++) {
        if ((p >> 1) == wr) {
            const int mb = (p & 1) << 1;
            #pragma unroll
            for (int mm = 0; mm < 2; mm++) {
                const int lrow = (mm << 4) + ((lane >> 4) << 2);
                #pragma unroll
                for (int n = 0; n < 4; n++) {
                    const int col = (wc << 6) + (n << 4) + (lane & 15);
                    #pragma unroll
                    for (int j = 0; j < 4; j++)
                        eb[(lrow + j) * 132 + col] = acc[mb + mm][n][j];
                }
            }
        }
        __syncthreads();
        #pragma unroll
        for (int i = 0; i < 4; i++) {
            int idx = (i << 8) + tid;        // 0..1023
            int row = idx >> 5, c4 = idx & 31;
            int gr = bm + (p << 5) + row;
            int gc = bn + (c4 << 2);
            size_t off = (size_t)gr * NT + gc;
            float4 v = *(float4*)&eb[row * 132 + (c4 << 2)];
            float4 e0v = *(const float4*)(e0 + gc);
            if (MODE == 1) {
                ushort4 xv = *(const ushort4*)(e1h + off);
                float y0 = v.x + e0v.x * bf2f(xv.x);
                float y1 = v.y + e0v.y * bf2f(xv.y);
                float y2 = v.z + e0v.z * bf2f(xv.z);
                float y3 = v.w + e0v.w * bf2f(xv.w);
                ushort4 a1, a2;
                a1.x = bf16bits(y0); a1.y = bf16bits(y1);
                a1.z = bf16bits(y2); a1.w = bf16bits(y3);
                a2.x = bf16bits(gelu_fast(y0)); a2.y = bf16bits(gelu_fast(y1));
                a2.z = bf16bits(gelu_fast(y2)); a2.w = bf16bits(gelu_fast(y3));
                *(ushort4*)(o1 + off) = a1;
                *(ushort4*)(o2 + off) = a2;
            } else {
                ushort4 yv = *(const ushort4*)(e1h + off);
                float4 xv = *(const float4*)(e2 + off);
                float4 o;
                o.x = xv.x + bf2f(yv.x) * sig_fast(v.x + e0v.x);
                o.y = xv.y + bf2f(yv.y) * sig_fast(v.y + e0v.y);
                o.z = xv.z + bf2f(yv.z) * sig_fast(v.z + e0v.z);
                o.w = xv.w + bf2f(yv.w) * sig_fast(v.w + e0v.w);
                *(float4*)(outF + off) = o;
            }
        }
        __syncthreads();
    }
}

// ---------------- launch ----------------
extern "C" void kernel_launch(void* const* d_in, const int* in_sizes, int n_in,
                              void* d_out, int out_size, void* d_ws, size_t ws_size,
                              hipStream_t stream)
{
    const float* x      = (const float*)d_in[0];
    const float* lr     = (const float*)d_in[1];
    const float* li     = (const float*)d_in[2];
    const float* b      = (const float*)d_in[3];
    const float* c      = (const float*)d_in[4];
    const float* d      = (const float*)d_in[5];
    const float* delta  = (const float*)d_in[6];
    const float* nsc    = (const float*)d_in[7];
    const float* noff   = (const float*)d_in[8];
    const float* w2     = (const float*)d_in[9];
    const float* b2     = (const float*)d_in[10];
    float* out = (float*)d_out;

    unsigned short* XNBF = (unsigned short*)d_ws;       // [L,H] bf16: xn -> gelu(y)
    unsigned short* YBF  = XNBF + (size_t)LSEQ * HF;    // [L,H] bf16: y
    unsigned short* XS16 = YBF + (size_t)LSEQ * HF;     // [L,2P] bf16: local xs
    unsigned short* XSBF = XS16 + (size_t)LSEQ * TWOP;  // [L,2P] bf16: corrected xs
    unsigned short* BWT  = XSBF + (size_t)LSEQ * TWOP;  // [2P,H] bf16
    unsigned short* CWT  = BWT + (size_t)TWOP * HF;     // [H,2P] bf16
    unsigned short* W2T  = CWT + (size_t)HF * TWOP;     // [H,H] bf16
    float* lam    = (float*)(W2T + (size_t)HF * HF);
    float* bls    = lam + TWOP;
    float* lamPow = bls + TWOP;                         // [(CL+1),2P]
    float* F      = lamPow + (size_t)(CL + 1) * TWOP;   // [NC,2P]
    float* G      = F + (size_t)NC * TWOP;              // [NC,2P]

    // params
    prep_lam_k<<<1, 128, 0, stream>>>(lr, li, delta, lam, bls, lamPow);
    prep_B_k<<<(PS * HF) / 256, 256, 0, stream>>>(b, bls, BWT);
    prep_C_k<<<(HF * PS) / 256, 256, 0, stream>>>(c, CWT);
    prep_w2_k<<<(HF * HF) / 256, 256, 0, stream>>>(w2, W2T);
    // layernorm -> bf16 xn
    ln_k<<<LSEQ, 128, 0, stream>>>(x, nsc, noff, XNBF);
    // Bu = xn * B_bar^T fused with local scan  [L,512]x[512,256]
    g1scan_k<<<dim3(TWOP >> 7, LSEQ >> 7), 256, 0, stream>>>(
        XNBF, BWT, XS16, F, lam);
    // Kogge-Stone carry scan over chunk finals
    carry_k<<<PS, 512, 0, stream>>>(F, G, lamPow);
    // parallel carry correction -> bf16 xs
    fix_k<<<NC * 4, 128, 0, stream>>>(XS16, G, lamPow, XSBF);
    // y = xs*Cw + d*xn -> bf16 y + bf16 gelu(y) (over xn)
    mgemm_k<1, TWOP, HF><<<dim3(4, LSEQ >> 7), 256, 0, stream>>>(
        XSBF, CWT, d, XNBF, nullptr, nullptr, YBF, XNBF);
    // out = x + y*sigmoid(x1@w2 + b2)
    mgemm_k<2, HF, HF><<<dim3(4, LSEQ >> 7), 256, 0, stream>>>(
        XNBF, W2T, b2, YBF, x, out, nullptr, nullptr);
}

// Round 13
// 225.411 us; speedup vs baseline: 1.8376x; 1.0497x over previous
//
#include <hip/hip_runtime.h>
#include <hip/hip_bf16.h>
#include <math.h>

#define LSEQ 32768
#define HF   512
#define PS   128      // state_size/2
#define TWOP 256      // 2*PS (interleaved re,im)
#define NC   512      // scan chunks
#define CL   64       // chunk length  (NC*CL == LSEQ)

typedef __attribute__((ext_vector_type(8))) short short8v;   // 8 bf16 (4 VGPRs)
typedef __attribute__((ext_vector_type(4))) float f32x4;     // MFMA acc

// ---------------- helpers ----------------
__device__ __forceinline__ float sig_fast(float z) {
    return __builtin_amdgcn_rcpf(1.0f + __expf(-z));
}
__device__ __forceinline__ float gelu_fast(float v) {
    // tanh-gelu == v * sigmoid(2*0.79788456*(v + 0.044715 v^3))
    float z = 1.5957691216057308f * v * fmaf(0.044715f, v * v, 1.0f);
    return v * sig_fast(z);
}
__device__ __forceinline__ unsigned short bf16bits(float f) {
    __hip_bfloat16 h = __float2bfloat16(f);
    return *(unsigned short*)&h;
}
__device__ __forceinline__ float bf2f(unsigned short u) {
    unsigned v = ((unsigned)u) << 16;
    return *(float*)&v;
}
__device__ __forceinline__ unsigned pk2(float a, float b) {
    return ((unsigned)bf16bits(b) << 16) | bf16bits(a);
}
__device__ __forceinline__ void gload_lds16(const void* g, void* l) {
    __builtin_amdgcn_global_load_lds(
        (const __attribute__((address_space(1))) unsigned int*)g,
        (__attribute__((address_space(3))) unsigned int*)l, 16, 0, 0);
}
__device__ __forceinline__ void wait_vm0_barrier() {
    asm volatile("s_waitcnt vmcnt(0)" ::: "memory");
    __builtin_amdgcn_s_barrier();
}

// ---------------- merged param prep (one dispatch) ----------------
// blk 0            : lam + lamPow (128 lanes)
// blk [1,257)      : BwT  (P*H)
// blk [257,513)    : CwT  (H*P)
// blk [513,1537)   : w2T  (H*H)
__global__ __launch_bounds__(256) void prep_all_k(
    const float* __restrict__ lr_, const float* __restrict__ li_,
    const float* __restrict__ delta, const float* __restrict__ b,
    const float* __restrict__ c, const float* __restrict__ w2,
    float* lam, float* lamPow,
    unsigned short* __restrict__ bwt, unsigned short* __restrict__ cwt,
    unsigned short* __restrict__ w2t)
{
    int blk = blockIdx.x, tid = threadIdx.x;
    if (blk == 0) {
        if (tid < 128) {
            int p = tid;
            float lr = lr_[p], li = li_[p];
            float step = expf(delta[p]);
            float s2 = 0.5f * step;
            float dr = 1.0f - s2 * lr, di = -s2 * li;
            float inv = 1.0f / (dr * dr + di * di);
            float blr = dr * inv, bli = -di * inv;
            float nr = 1.0f + s2 * lr, ni = s2 * li;
            float lbr = blr * nr - bli * ni;
            float lbi = blr * ni + bli * nr;
            lam[2 * p] = lbr; lam[2 * p + 1] = lbi;
            float pr = 1.0f, pim = 0.0f;
            lamPow[2 * p] = 1.0f; lamPow[2 * p + 1] = 0.0f;
            for (int k = 1; k <= CL; k++) {
                float t = pr * lbr - pim * lbi;
                pim = pr * lbi + pim * lbr;
                pr = t;
                lamPow[k * TWOP + 2 * p] = pr;
                lamPow[k * TWOP + 2 * p + 1] = pim;
            }
        }
    } else if (blk < 257) {
        int idx = (blk - 1) * 256 + tid;   // over P*H
        int p = idx >> 9, h = idx & 511;
        // recompute bl*step inline (no cross-block dependency)
        float lr = lr_[p], li = li_[p];
        float step = expf(delta[p]);
        float s2 = 0.5f * step;
        float dr = 1.0f - s2 * lr, di = -s2 * li;
        float inv = 1.0f / (dr * dr + di * di);
        float sr = dr * inv * step, si = -di * inv * step;
        float2 bb = *(const float2*)(b + ((size_t)p * HF + h) * 2);
        bwt[(size_t)(2 * p) * HF + h]     = bf16bits(sr * bb.x - si * bb.y);
        bwt[(size_t)(2 * p + 1) * HF + h] = bf16bits(sr * bb.y + si * bb.x);
    } else if (blk < 513) {
        int idx = (blk - 257) * 256 + tid; // over H*P
        int h = idx >> 7, p = idx & 127;
        float2 cc = *(const float2*)(c + ((size_t)h * PS + p) * 2);
        *(unsigned*)(cwt + (size_t)h * TWOP + 2 * p) = pk2(2.0f * cc.x, -2.0f * cc.y);
    } else {
        int idx = (blk - 513) * 256 + tid; // over H*H
        int n = idx >> 9, k = idx & 511;
        w2t[(size_t)n * HF + k] = bf16bits(w2[(size_t)k * HF + n]);
    }
}

// ---------------- LayerNorm: 1 wave/row, 8 elems/lane, 16B stores ----------
__global__ __launch_bounds__(128) void ln_k(
    const float* __restrict__ x, const float* __restrict__ scale,
    const float* __restrict__ offs, unsigned short* __restrict__ xnbf)
{
    int w = threadIdx.x >> 6, l = threadIdx.x & 63;
    int row = (blockIdx.x << 1) + w;
    const float4* xr = (const float4*)(x + (size_t)row * HF);
    float4 a = xr[2 * l], b4 = xr[2 * l + 1];
    float s = a.x + a.y + a.z + a.w + b4.x + b4.y + b4.z + b4.w;
    float q = a.x * a.x + a.y * a.y + a.z * a.z + a.w * a.w
            + b4.x * b4.x + b4.y * b4.y + b4.z * b4.z + b4.w * b4.w;
    #pragma unroll
    for (int off = 32; off > 0; off >>= 1) {
        s += __shfl_down(s, off);
        q += __shfl_down(q, off);
    }
    s = __shfl(s, 0); q = __shfl(q, 0);
    float mean = s * (1.0f / HF);
    float var = q * (1.0f / HF) - mean * mean;
    float rstd = rsqrtf(var + 1e-5f);
    float4 sc0 = ((const float4*)scale)[2 * l], sc1 = ((const float4*)scale)[2 * l + 1];
    float4 of0 = ((const float4*)offs)[2 * l],  of1 = ((const float4*)offs)[2 * l + 1];
    float y0 = (a.x - mean) * rstd * sc0.x + of0.x;
    float y1 = (a.y - mean) * rstd * sc0.y + of0.y;
    float y2 = (a.z - mean) * rstd * sc0.z + of0.z;
    float y3 = (a.w - mean) * rstd * sc0.w + of0.w;
    float y4 = (b4.x - mean) * rstd * sc1.x + of1.x;
    float y5 = (b4.y - mean) * rstd * sc1.y + of1.y;
    float y6 = (b4.z - mean) * rstd * sc1.z + of1.z;
    float y7 = (b4.w - mean) * rstd * sc1.w + of1.w;
    uint4 o;
    o.x = pk2(y0, y1); o.y = pk2(y2, y3);
    o.z = pk2(y4, y5); o.w = pk2(y6, y7);
    *(uint4*)(xnbf + (size_t)row * HF + l * 8) = o;
}

// ---------------- fused GEMM1 + local scan (2-phase pipelined) ----------------
__global__ __launch_bounds__(256) void g1scan_k(
    const unsigned short* __restrict__ A,   // XNBF [L][HF]
    const unsigned short* __restrict__ Bt,  // BWT  [TWOP][HF]
    unsigned short* __restrict__ xs16,      // [L][TWOP] bf16 local xs
    float* __restrict__ F,                  // [NC][TWOP]
    const float* __restrict__ lam)
{
    __shared__ float yt[128 * 128];         // 64KB; first 32KB doubles as dbuf staging
    unsigned short* Sb = (unsigned short*)yt;   // buf b: A at b*8192, B at b*8192+4096
    const int K = HF;
    // XCD-chunked swizzle (nwg=512, gx=2)
    int flat = (blockIdx.y << 1) + blockIdx.x;
    int f2 = (flat & 7) * 64 + (flat >> 3);
    const int bxi = f2 & 1, byi = f2 >> 1;
    const int bm = byi << 7;
    const int bn = bxi << 7;
    const int tid = threadIdx.x;
    const int lane = tid & 63;
    const int wid = tid >> 6;
    const int wr = wid >> 1, wc = wid & 1;

    f32x4 acc[4][4] = {};

    const int r0 = (wid << 5) + (lane >> 2);
    const int c0 = (lane & 3) << 3;
    const unsigned short* gA = A + (size_t)(bm + r0) * K + c0;
    const unsigned short* gB = Bt + (size_t)(bn + r0) * K + c0;
    const int stA0 = (wid << 5) * 32;
    const int stA1 = ((wid << 5) + 16) * 32;
    const int aoff = ((wr << 6) + (lane & 15)) * 32 + ((lane >> 4) << 3);
    const int boff = ((wc << 6) + (lane & 15)) * 32 + ((lane >> 4) << 3);

    #define G1_STAGE(b, k0) do { \
        gload_lds16(gA + (k0), Sb + (b) * 8192 + stA0); \
        gload_lds16(gA + (k0) + (size_t)16 * K, Sb + (b) * 8192 + stA1); \
        gload_lds16(gB + (k0), Sb + (b) * 8192 + 4096 + stA0); \
        gload_lds16(gB + (k0) + (size_t)16 * K, Sb + (b) * 8192 + 4096 + stA1); \
    } while (0)
    #define G1_COMPUTE(b) do { \
        short8v a_[4], b_[4]; \
        _Pragma("unroll") \
        for (int m = 0; m < 4; m++) \
            a_[m] = *(const short8v*)(Sb + (b) * 8192 + aoff + (m << 4) * 32); \
        _Pragma("unroll") \
        for (int n = 0; n < 4; n++) \
            b_[n] = *(const short8v*)(Sb + (b) * 8192 + 4096 + boff + (n << 4) * 32); \
        _Pragma("unroll") \
        for (int m = 0; m < 4; m++) \
            _Pragma("unroll") \
            for (int n = 0; n < 4; n++) \
                acc[m][n] = __builtin_amdgcn_mfma_f32_16x16x32_bf16( \
                    a_[m], b_[n], acc[m][n], 0, 0, 0); \
    } while (0)

    G1_STAGE(0, 0);
    wait_vm0_barrier();
    #pragma unroll
    for (int t = 0; t < 16; ++t) {
        const int cur = t & 1;
        if (t + 1 < 16) G1_STAGE(cur ^ 1, (t + 1) << 5);
        G1_COMPUTE(cur);
        wait_vm0_barrier();
    }

    // acc -> LDS tile (row-major [128][128])
    #pragma unroll
    for (int m = 0; m < 4; m++) {
        const int rowb = (wr << 6) + (m << 4) + ((lane >> 4) << 2);
        #pragma unroll
        for (int n = 0; n < 4; n++) {
            const int col = (wc << 6) + (n << 4) + (lane & 15);
            #pragma unroll
            for (int j = 0; j < 4; j++)
                yt[(rowb + j) * 128 + col] = acc[m][n][j];
        }
    }
    __syncthreads();

    // local scan: 128 threads, each owns (chunk, complex pair)
    if (tid < 128) {
        int ch = tid >> 6, q = tid & 63;
        int pg = (bxi << 6) + q;                 // global pair index
        float lr = lam[2 * pg], liv = lam[2 * pg + 1];
        float sr = 0.0f, si = 0.0f;
        float* col = yt + (ch << 6) * 128 + 2 * q;
        #pragma unroll 8
        for (int i = 0; i < CL; i++) {
            float ur = col[i * 128], ui = col[i * 128 + 1];
            float tr = lr * sr - liv * si + ur;
            float ti = lr * si + liv * sr + ui;
            sr = tr; si = ti;
            col[i * 128] = sr; col[i * 128 + 1] = si;
        }
        int cg = (byi << 1) + ch;
        F[(size_t)cg * TWOP + (bxi << 7) + 2 * q] = sr;
        F[(size_t)cg * TWOP + (bxi << 7) + 2 * q + 1] = si;
    }
    __syncthreads();

    // write tile to global xs16 as bf16 (16B = 8 vals)
    #pragma unroll
    for (int j = 0; j < 8; j++) {
        int fl = j * 256 + tid;
        int r = fl >> 4, ck = fl & 15;
        float4 v0 = *(float4*)&yt[r * 128 + ck * 8];
        float4 v1 = *(float4*)&yt[r * 128 + ck * 8 + 4];
        uint4 o;
        o.x = pk2(v0.x, v0.y); o.y = pk2(v0.z, v0.w);
        o.z = pk2(v1.x, v1.y); o.w = pk2(v1.z, v1.w);
        *(uint4*)(xs16 + (size_t)(bm + r) * TWOP + bn + ck * 8) = o;
    }
}

// ---------------- carry scan: Kogge-Stone over chunk finals ----------------
__global__ __launch_bounds__(512) void carry_k(
    const float* __restrict__ F, float* __restrict__ G,
    const float* __restrict__ lamPow)
{
    __shared__ float2 buf[NC];
    int c = threadIdx.x, p = blockIdx.x;
    float2 f = *(const float2*)(F + (size_t)c * TWOP + 2 * p);
    buf[c] = f;
    float aR = lamPow[CL * TWOP + 2 * p], aI = lamPow[CL * TWOP + 2 * p + 1];
    __syncthreads();
    #pragma unroll
    for (int d = 1; d < NC; d <<= 1) {
        bool act = (c >= d);
        float2 pv = act ? buf[c - d] : make_float2(0.0f, 0.0f);
        __syncthreads();
        if (act) {
            float2 cur = buf[c];
            cur.x += aR * pv.x - aI * pv.y;
            cur.y += aR * pv.y + aI * pv.x;
            buf[c] = cur;
        }
        __syncthreads();
        float nR = aR * aR - aI * aI;
        float nI = 2.0f * aR * aI;
        aR = nR; aI = nI;
    }
    *(float2*)(G + (size_t)c * TWOP + 2 * p) = buf[c];
}

// ---------------- parallel carry correction (16B granularity) --------------
// block = chunk c (512 blocks) x 128 threads; thread (rsub=tid>>5, g=tid&31)
// handles pairs 4g..4g+3 over rows rsub, rsub+4, ..., rsub+60.
__global__ __launch_bounds__(128) void fix_k(
    const unsigned short* __restrict__ xs16, const float* __restrict__ G,
    const float* __restrict__ lamPow, unsigned short* __restrict__ xsbf)
{
    int c = blockIdx.x;
    int g = threadIdx.x & 31, rsub = threadIdx.x >> 5;
    float gr[4], gi[4];
    if (c > 0) {
        float4 ga = *(const float4*)(G + (size_t)(c - 1) * TWOP + g * 8);
        float4 gb = *(const float4*)(G + (size_t)(c - 1) * TWOP + g * 8 + 4);
        gr[0] = ga.x; gi[0] = ga.y; gr[1] = ga.z; gi[1] = ga.w;
        gr[2] = gb.x; gi[2] = gb.y; gr[3] = gb.z; gi[3] = gb.w;
    } else {
        gr[0] = gr[1] = gr[2] = gr[3] = 0.0f;
        gi[0] = gi[1] = gi[2] = gi[3] = 0.0f;
    }
    #pragma unroll
    for (int i = 0; i < 16; i++) {
        int row = (i << 2) + rsub;                 // 0..63
        size_t boff = ((size_t)c * CL + row) * TWOP + g * 8;
        uint4 u = *(const uint4*)(xs16 + boff);
        float4 la = *(const float4*)(lamPow + (size_t)(row + 1) * TWOP + g * 8);
        float4 lb = *(const float4*)(lamPow + (size_t)(row + 1) * TWOP + g * 8 + 4);
        float lpr[4] = {la.x, la.z, lb.x, lb.z};
        float lpi[4] = {la.y, la.w, lb.y, lb.w};
        unsigned uu[4] = {u.x, u.y, u.z, u.w};
        uint4 o;
        unsigned* oo = (unsigned*)&o;
        #pragma unroll
        for (int j = 0; j < 4; j++) {
            float vr = bf2f((unsigned short)(uu[j] & 0xffff)) + lpr[j] * gr[j] - lpi[j] * gi[j];
            float vi = bf2f((unsigned short)(uu[j] >> 16))    + lpr[j] * gi[j] + lpi[j] * gr[j];
            oo[j] = pk2(vr, vi);
        }
        *(uint4*)(xsbf + boff) = o;
    }
}

// ---------------- bf16 MFMA GEMM (2-phase pipelined, 16B epilogue I/O) ------
// MODE 1: y = acc + e0[col]*xn;  o1 = bf16(y); o2 = bf16(gelu(y))  (o2 aliases e1h)
// MODE 2: outF = e2 + bf2f(e1h)*sigmoid(acc + e0[col])
template<int MODE, int KT, int NT>
__global__ __launch_bounds__(256) void mgemm_k(
    const unsigned short* __restrict__ A, const unsigned short* __restrict__ Bt,
    const float* __restrict__ e0, const unsigned short* __restrict__ e1h,
    const float* __restrict__ e2, float* __restrict__ outF,
    unsigned short* __restrict__ o1, unsigned short* __restrict__ o2)
{
    __shared__ float smem[8192];            // 32KB: dbuf staging; eb aliases base
    unsigned short* Sb = (unsigned short*)smem; // buf b: A at b*8192, B at b*8192+4096
    float* eb = smem;                            // [32][132] padded fp32 (16.9KB)

    // XCD-chunked swizzle (nwg = (NT>>7)*256, divisible by 8)
    constexpr int GX = NT >> 7;
    int flat = blockIdx.y * GX + blockIdx.x;
    constexpr int NWG = GX * (LSEQ >> 7);
    int f2 = (flat & 7) * (NWG >> 3) + (flat >> 3);
    const int bm = (f2 / GX) << 7;
    const int bn = (f2 % GX) << 7;

    const int tid = threadIdx.x;
    const int lane = tid & 63;
    const int wid = tid >> 6;
    const int wr = wid >> 1, wc = wid & 1;

    f32x4 acc[4][4] = {};

    const int r0 = (wid << 5) + (lane >> 2);
    const int c0 = (lane & 3) << 3;
    const unsigned short* gA = A + (size_t)(bm + r0) * KT + c0;
    const unsigned short* gB = Bt + (size_t)(bn + r0) * KT + c0;
    const int stA0 = (wid << 5) * 32;
    const int stA1 = ((wid << 5) + 16) * 32;
    const int aoff = ((wr << 6) + (lane & 15)) * 32 + ((lane >> 4) << 3);
    const int boff = ((wc << 6) + (lane & 15)) * 32 + ((lane >> 4) << 3);
    constexpr int NSTEP = KT >> 5;

    #define MG_STAGE(b, k0) do { \
        gload_lds16(gA + (k0), Sb + (b) * 8192 + stA0); \
        gload_lds16(gA + (k0) + (size_t)16 * KT, Sb + (b) * 8192 + stA1); \
        gload_lds16(gB + (k0), Sb + (b) * 8192 + 4096 + stA0); \
        gload_lds16(gB + (k0) + (size_t)16 * KT, Sb + (b) * 8192 + 4096 + stA1); \
    } while (0)
    #define MG_COMPUTE(b) do { \
        short8v a_[4], b_[4]; \
        _Pragma("unroll") \
        for (int m = 0; m < 4; m++) \
            a_[m] = *(const short8v*)(Sb + (b) * 8192 + aoff + (m << 4) * 32); \
        _Pragma("unroll") \
        for (int n = 0; n < 4; n++) \
            b_[n] = *(const short8v*)(Sb + (b) * 8192 + 4096 + boff + (n << 4) * 32); \
        _Pragma("unroll") \
        for (int m = 0; m < 4; m++) \
            _Pragma("unroll") \
            for (int n = 0; n < 4; n++) \
                acc[m][n] = __builtin_amdgcn_mfma_f32_16x16x32_bf16( \
                    a_[m], b_[n], acc[m][n], 0, 0, 0); \
    } while (0)

    MG_STAGE(0, 0);
    wait_vm0_barrier();
    #pragma unroll
    for (int t = 0; t < NSTEP; ++t) {
        const int cur = t & 1;
        if (t + 1 < NSTEP) MG_STAGE(cur ^ 1, (t + 1) << 5);
        MG_COMPUTE(cur);
        wait_vm0_barrier();
    }

    // epilogue: 4 passes of 32 rows through padded LDS; 16B global I/O
    #pragma unroll
    for (int p = 0; p < 4; p++) {
        if ((p >> 1) == wr) {
            const int mb = (p & 1) << 1;
            #pragma unroll
            for (int mm = 0; mm < 2; mm++) {
                const int lrow = (mm << 4) + ((lane >> 4) << 2);
                #pragma unroll
                for (int n = 0; n < 4; n++) {
                    const int col = (wc << 6) + (n << 4) + (lane & 15);
                    #pragma unroll
                    for (int j = 0; j < 4; j++)
                        eb[(lrow + j) * 132 + col] = acc[mb + mm][n][j];
                }
            }
        }
        __syncthreads();
        #pragma unroll
        for (int i = 0; i < 2; i++) {
            int idx = (i << 8) + tid;        // 0..511
            int row = idx >> 4, cp = idx & 15;   // 32 rows x 16 col-groups of 8
            int gr = bm + (p << 5) + row;
            int gc = bn + (cp << 3);
            size_t off = (size_t)gr * NT + gc;
            float4 v0 = *(float4*)&eb[row * 132 + (cp << 3)];
            float4 v1 = *(float4*)&eb[row * 132 + (cp << 3) + 4];
            float4 e0a = *(const float4*)(e0 + gc);
            float4 e0b = *(const float4*)(e0 + gc + 4);
            uint4 hv = *(const uint4*)(e1h + off);
            const unsigned* hh = (const unsigned*)&hv;
            float ev[8] = {e0a.x, e0a.y, e0a.z, e0a.w, e0b.x, e0b.y, e0b.z, e0b.w};
            float av[8] = {v0.x, v0.y, v0.z, v0.w, v1.x, v1.y, v1.z, v1.w};
            if (MODE == 1) {
                float y[8];
                #pragma unroll
                for (int j = 0; j < 8; j++) {
                    unsigned short xb = (j & 1) ? (unsigned short)(hh[j >> 1] >> 16)
                                                : (unsigned short)(hh[j >> 1] & 0xffff);
                    y[j] = av[j] + ev[j] * bf2f(xb);
                }
                uint4 a1, a2;
                unsigned* p1 = (unsigned*)&a1;
                unsigned* p2 = (unsigned*)&a2;
                #pragma unroll
                for (int j = 0; j < 4; j++) {
                    p1[j] = pk2(y[2 * j], y[2 * j + 1]);
                    p2[j] = pk2(gelu_fast(y[2 * j]), gelu_fast(y[2 * j + 1]));
                }
                *(uint4*)(o1 + off) = a1;
                *(uint4*)(o2 + off) = a2;
            } else {
                float4 x0 = *(const float4*)(e2 + off);
                float4 x1 = *(const float4*)(e2 + off + 4);
                float xv[8] = {x0.x, x0.y, x0.z, x0.w, x1.x, x1.y, x1.z, x1.w};
                float o[8];
                #pragma unroll
                for (int j = 0; j < 8; j++) {
                    unsigned short yb = (j & 1) ? (unsigned short)(hh[j >> 1] >> 16)
                                                : (unsigned short)(hh[j >> 1] & 0xffff);
                    o[j] = xv[j] + bf2f(yb) * sig_fast(av[j] + ev[j]);
                }
                *(float4*)(outF + off)     = make_float4(o[0], o[1], o[2], o[3]);
                *(float4*)(outF + off + 4) = make_float4(o[4], o[5], o[6], o[7]);
            }
        }
        __syncthreads();
    }
}

// ---------------- launch ----------------
extern "C" void kernel_launch(void* const* d_in, const int* in_sizes, int n_in,
                              void* d_out, int out_size, void* d_ws, size_t ws_size,
                              hipStream_t stream)
{
    const float* x      = (const float*)d_in[0];
    const float* lr     = (const float*)d_in[1];
    const float* li     = (const float*)d_in[2];
    const float* b      = (const float*)d_in[3];
    const float* c      = (const float*)d_in[4];
    const float* d      = (const float*)d_in[5];
    const float* delta  = (const float*)d_in[6];
    const float* nsc    = (const float*)d_in[7];
    const float* noff   = (const float*)d_in[8];
    const float* w2     = (const float*)d_in[9];
    const float* b2     = (const float*)d_in[10];
    float* out = (float*)d_out;

    unsigned short* XNBF = (unsigned short*)d_ws;       // [L,H] bf16: xn -> gelu(y)
    unsigned short* YBF  = XNBF + (size_t)LSEQ * HF;    // [L,H] bf16: y
    unsigned short* XS16 = YBF + (size_t)LSEQ * HF;     // [L,2P] bf16: local xs
    unsigned short* XSBF = XS16 + (size_t)LSEQ * TWOP;  // [L,2P] bf16: corrected xs
    unsigned short* BWT  = XSBF + (size_t)LSEQ * TWOP;  // [2P,H] bf16
    unsigned short* CWT  = BWT + (size_t)TWOP * HF;     // [H,2P] bf16
    unsigned short* W2T  = CWT + (size_t)HF * TWOP;     // [H,H] bf16
    float* lam    = (float*)(W2T + (size_t)HF * HF);
    float* lamPow = lam + TWOP;                         // [(CL+1),2P]
    float* F      = lamPow + (size_t)(CL + 1) * TWOP;   // [NC,2P]
    float* G      = F + (size_t)NC * TWOP;              // [NC,2P]

    // merged params (1537 blocks)
    prep_all_k<<<1537, 256, 0, stream>>>(lr, li, delta, b, c, w2,
                                         lam, lamPow, BWT, CWT, W2T);
    // layernorm -> bf16 xn (2 rows/block, 1 wave/row)
    ln_k<<<LSEQ / 2, 128, 0, stream>>>(x, nsc, noff, XNBF);
    // Bu = xn * B_bar^T fused with local scan  [L,512]x[512,256]
    g1scan_k<<<dim3(TWOP >> 7, LSEQ >> 7), 256, 0, stream>>>(
        XNBF, BWT, XS16, F, lam);
    // Kogge-Stone carry scan over chunk finals
    carry_k<<<PS, 512, 0, stream>>>(F, G, lamPow);
    // parallel carry correction -> bf16 xs
    fix_k<<<NC, 128, 0, stream>>>(XS16, G, lamPow, XSBF);
    // y = xs*Cw + d*xn -> bf16 y + bf16 gelu(y) (over xn)
    mgemm_k<1, TWOP, HF><<<dim3(4, LSEQ >> 7), 256, 0, stream>>>(
        XSBF, CWT, d, XNBF, nullptr, nullptr, YBF, XNBF);
    // out = x + y*sigmoid(x1@w2 + b2)
    mgemm_k<2, HF, HF><<<dim3(4, LSEQ >> 7), 256, 0, stream>>>(
        XNBF, W2T, b2, YBF, x, out, nullptr, nullptr);
}